// Round 1
// baseline (1225.545 us; speedup 1.0000x reference)
//
#include <hip/hip_runtime.h>

#define N_NODES 50000
#define N_EDGES 1600000
#define IN_CH   256
#define ADP     64
#define EDGE_DIM 32

// ---------------- K1: node_feat = relu(x @ W_down^T + b_down) ----------------
// W_down [64][256] staged transposed+swizzled in 64KB LDS: elem (c,k) at
// lds[k*64 + (c ^ (k&31))] -> conflict-free reads (fixed k, lanes c) and writes.
__global__ __launch_bounds__(256) void k_down(const float* __restrict__ x,
                                              const float* __restrict__ Wd,
                                              const float* __restrict__ bd,
                                              float* __restrict__ node_feat) {
    __shared__ float lds[IN_CH * ADP];  // 64KB
    for (int idx = threadIdx.x; idx < IN_CH * ADP; idx += 256) {
        int c = idx >> 8;        // row of W_down
        int k = idx & 255;       // col
        lds[k * ADP + (c ^ (k & 31))] = Wd[idx];
    }
    __syncthreads();
    int wave = threadIdx.x >> 6;
    int lane = threadIdx.x & 63;
    float b = bd[lane];
    for (int n = blockIdx.x * 4 + wave; n < N_NODES; n += gridDim.x * 4) {
        const float4* x4 = (const float4*)(x + (size_t)n * IN_CH);
        float acc = b;
        #pragma unroll 8
        for (int k4 = 0; k4 < IN_CH / 4; k4++) {
            float4 v = x4[k4];
            int k = k4 * 4;
            acc += v.x * lds[(k + 0) * ADP + (lane ^ ((k + 0) & 31))];
            acc += v.y * lds[(k + 1) * ADP + (lane ^ ((k + 1) & 31))];
            acc += v.z * lds[(k + 2) * ADP + (lane ^ ((k + 2) & 31))];
            acc += v.w * lds[(k + 3) * ADP + (lane ^ ((k + 3) & 31))];
        }
        node_feat[n * ADP + lane] = fmaxf(acc, 0.f);
    }
}

// ---------------- K2: per-edge time-proj + scatter-add -----------------------
// One wave per edge (grid-stride). Lane c holds W_time row c (32 VGPRs).
// attr loads are wave-uniform-address float4 (broadcast). 64 contiguous-address
// atomics per edge into sums[src*64 + c]; lane 0 bumps counts[src].
__global__ __launch_bounds__(256) void k_edge(const float* __restrict__ ea,
                                              const int* __restrict__ ei_src,
                                              const float* __restrict__ Wt,
                                              const float* __restrict__ bt,
                                              float* __restrict__ sums,
                                              float* __restrict__ counts) {
    int lane = threadIdx.x & 63;
    float w[EDGE_DIM];
    #pragma unroll
    for (int k = 0; k < EDGE_DIM; k++) w[k] = Wt[lane * EDGE_DIM + k];
    float b = bt[lane];
    int wave_global = blockIdx.x * 4 + (threadIdx.x >> 6);
    int nwaves = gridDim.x * 4;
    for (int e = wave_global; e < N_EDGES; e += nwaves) {
        const float4* a4 = (const float4*)(ea + (size_t)e * EDGE_DIM);
        float acc = b;
        #pragma unroll
        for (int k4 = 0; k4 < EDGE_DIM / 4; k4++) {
            float4 v = a4[k4];
            acc += v.x * w[4 * k4 + 0] + v.y * w[4 * k4 + 1]
                 + v.z * w[4 * k4 + 2] + v.w * w[4 * k4 + 3];
        }
        int src = ei_src[e];
        float val = fmaxf(acc, 0.f);
        atomicAdd(&sums[(size_t)src * ADP + lane], val);
        if (lane == 0) atomicAdd(&counts[src], 1.f);
    }
}

// ---------------- K3a: fused = relu(W_fusion @ [node_feat | mean] + b) -------
// W_fusion [64][128] staged in 32KB LDS at lds[k*64 + (c ^ (k&31))].
__global__ __launch_bounds__(256) void k_fuse(const float* __restrict__ node_feat,
                                              const float* __restrict__ sums,
                                              const float* __restrict__ counts,
                                              const float* __restrict__ Wf,
                                              const float* __restrict__ bf,
                                              float* __restrict__ fused) {
    __shared__ float lds[2 * ADP * ADP];  // 32KB, [k(128)][c(64)] swizzled
    for (int idx = threadIdx.x; idx < 2 * ADP * ADP; idx += 256) {
        int c = idx >> 7;        // row of W_fusion
        int k = idx & 127;       // col
        lds[k * ADP + (c ^ (k & 31))] = Wf[idx];
    }
    __syncthreads();
    int wave = threadIdx.x >> 6;
    int lane = threadIdx.x & 63;
    float b = bf[lane];
    for (int n = blockIdx.x * 4 + wave; n < N_NODES; n += gridDim.x * 4) {
        float inv = 1.f / fmaxf(counts[n], 1.f);
        const float* nf = node_feat + (size_t)n * ADP;
        const float* sm = sums + (size_t)n * ADP;
        float acc = b;
        #pragma unroll 4
        for (int k = 0; k < ADP; k++)
            acc += nf[k] * lds[k * ADP + (lane ^ (k & 31))];
        #pragma unroll 4
        for (int k = 0; k < ADP; k++)
            acc += (sm[k] * inv) * lds[(k + ADP) * ADP + (lane ^ ((k + ADP) & 31))];
        fused[n * ADP + lane] = fmaxf(acc, 0.f);
    }
}

// ---------------- K3b: out = x + fused @ W_up^T + b_up -----------------------
// Thread t (0..255) holds W_up row t in 64 VGPRs; fused row read broadcast.
__global__ __launch_bounds__(256) void k_up(const float* __restrict__ fused,
                                            const float* __restrict__ x,
                                            const float* __restrict__ Wu,
                                            const float* __restrict__ bu,
                                            float* __restrict__ out) {
    int t = threadIdx.x;
    float w[ADP];
    #pragma unroll
    for (int k = 0; k < ADP; k++) w[k] = Wu[t * ADP + k];
    float b = bu[t];
    for (int n = blockIdx.x; n < N_NODES; n += gridDim.x) {
        const float4* f4 = (const float4*)(fused + (size_t)n * ADP);
        float acc = b;
        #pragma unroll
        for (int k4 = 0; k4 < ADP / 4; k4++) {
            float4 v = f4[k4];
            acc += v.x * w[4 * k4 + 0] + v.y * w[4 * k4 + 1]
                 + v.z * w[4 * k4 + 2] + v.w * w[4 * k4 + 3];
        }
        size_t off = (size_t)n * IN_CH + t;
        out[off] = x[off] + acc;
    }
}

extern "C" void kernel_launch(void* const* d_in, const int* in_sizes, int n_in,
                              void* d_out, int out_size, void* d_ws, size_t ws_size,
                              hipStream_t stream) {
    const float* x   = (const float*)d_in[0];
    const int*   ei  = (const int*)d_in[1];     // [2, E] int; row 0 = src
    const float* ea  = (const float*)d_in[2];
    const float* Wd  = (const float*)d_in[3];
    const float* bd  = (const float*)d_in[4];
    const float* Wt  = (const float*)d_in[5];
    const float* bt  = (const float*)d_in[6];
    const float* Wf  = (const float*)d_in[7];
    const float* bf  = (const float*)d_in[8];
    const float* Wu  = (const float*)d_in[9];
    const float* bu  = (const float*)d_in[10];
    float* out = (float*)d_out;

    // workspace layout (floats): sums[N*64] | counts[N] | node_feat[N*64] | fused[N*64]
    float* sums      = (float*)d_ws;
    float* counts    = sums + (size_t)N_NODES * ADP;
    float* node_feat = counts + N_NODES;
    float* fused     = node_feat + (size_t)N_NODES * ADP;

    // zero sums + counts (contiguous at start of ws)
    hipMemsetAsync(d_ws, 0, ((size_t)N_NODES * ADP + N_NODES) * sizeof(float), stream);

    k_down<<<1024, 256, 0, stream>>>(x, Wd, bd, node_feat);
    k_edge<<<2048, 256, 0, stream>>>(ea, ei, Wt, bt, sums, counts);
    k_fuse<<<1024, 256, 0, stream>>>(node_feat, sums, counts, Wf, bf, fused);
    k_up<<<4096, 256, 0, stream>>>(fused, x, Wu, bu, out);
}